// Round 1
// baseline (384.441 us; speedup 1.0000x reference)
//
#include <hip/hip_runtime.h>
#include <math.h>

#define BATCH 8
#define S 512
#define SS (S * S)          // 262144 = 2^18
#define KMAX 16
#define EMPTY_DIST 362.1f

// ws float-word layout:
// [0..8)    per-batch max of _distance (atomicMax on int bits; values >= 0)
// [8..16)   per-batch sum of pred*_distance (float atomicAdd)
// [16]      gradient sum (float atomicAdd)
// [24..32)  per-batch highlight counts (int)
// [64..64+8*32) per-batch points: 16 x {y,x} floats

__device__ __forceinline__ float blockReduceSum(float v) {
    __shared__ float smem[4];
    int lane = threadIdx.x & 63;
    int wave = threadIdx.x >> 6;
#pragma unroll
    for (int off = 32; off > 0; off >>= 1) v += __shfl_down(v, off, 64);
    if (lane == 0) smem[wave] = v;
    __syncthreads();
    if (wave == 0) {
        v = (lane < 4) ? smem[lane] : 0.0f;
        v += __shfl_down(v, 2, 64);
        v += __shfl_down(v, 1, 64);
    }
    return v;  // valid in thread 0
}

__device__ __forceinline__ float blockReduceMax(float v) {
    __shared__ float smem[4];
    int lane = threadIdx.x & 63;
    int wave = threadIdx.x >> 6;
#pragma unroll
    for (int off = 32; off > 0; off >>= 1) v = fmaxf(v, __shfl_down(v, off, 64));
    if (lane == 0) smem[wave] = v;
    __syncthreads();
    if (wave == 0) {
        v = (lane < 4) ? smem[lane] : 0.0f;
        v = fmaxf(v, __shfl_down(v, 2, 64));
        v = fmaxf(v, __shfl_down(v, 1, 64));
    }
    return v;
}

__global__ __launch_bounds__(256) void k_init(float* ws) {
    int i = blockIdx.x * 256 + threadIdx.x;
    if (i < 512) ws[i] = 0.0f;  // zeroes maxes, sums, grad, counts, points
}

__global__ __launch_bounds__(256) void k_find(const float* __restrict__ ptl,
                                              int* __restrict__ counts,
                                              float* __restrict__ pts) {
    int idx = blockIdx.x * 256 + threadIdx.x;  // 0 .. BATCH*SS-1
    float v = ptl[idx];
    if (v != 0.0f) {
        int b = idx >> 18;
        int i = idx & (SS - 1);
        int slot = atomicAdd(&counts[b], 1);
        if (slot < KMAX) {
            pts[b * 2 * KMAX + 2 * slot]     = (float)(i >> 9);   // y
            pts[b * 2 * KMAX + 2 * slot + 1] = (float)(i & 511);  // x
        }
    }
}

__device__ __forceinline__ float dist_val(int i, int cnt, const float* pts_b) {
    float py = (float)(i >> 9);
    float px = (float)(i & 511);
    float dmin2 = 1e30f;
#pragma unroll 4
    for (int k = 0; k < cnt; k++) {
        float dy = py - pts_b[2 * k];
        float dx = px - pts_b[2 * k + 1];
        float d2 = dy * dy + dx * dx;
        dmin2 = fminf(dmin2, d2);
    }
    float dmin = (cnt > 0) ? sqrtf(dmin2) : EMPTY_DIST;
    // distance_thre == 1
    return (dmin > 1.0f) ? (dmin - 1.0f) : 0.0f;
}

__global__ __launch_bounds__(256) void k_dmax(const int* __restrict__ counts,
                                              const float* __restrict__ pts,
                                              int* __restrict__ maxes_bits) {
    int b = blockIdx.y;
    int i = blockIdx.x * 256 + threadIdx.x;  // pixel in image
    int cnt = counts[b];
    if (cnt > KMAX) cnt = KMAX;
    float dd = dist_val(i, cnt, pts + b * 2 * KMAX);
    float m = blockReduceMax(dd);
    if (threadIdx.x == 0) atomicMax(&maxes_bits[b], __float_as_int(m));
}

__global__ __launch_bounds__(256) void k_dsum(const float* __restrict__ pred,
                                              const int* __restrict__ counts,
                                              const float* __restrict__ pts,
                                              float* __restrict__ sums) {
    int b = blockIdx.y;
    int i = blockIdx.x * 256 + threadIdx.x;
    int cnt = counts[b];
    if (cnt > KMAX) cnt = KMAX;
    float dd = dist_val(i, cnt, pts + b * 2 * KMAX);
    float v = pred[b * SS + i] * dd;
    float s = blockReduceSum(v);
    if (threadIdx.x == 0) atomicAdd(&sums[b], s);
}

__global__ __launch_bounds__(256) void k_grad(const float* __restrict__ pred,
                                              const float* __restrict__ ori,
                                              float* __restrict__ gradsum) {
    int idx = blockIdx.x * 256 + threadIdx.x;  // 0 .. BATCH*SS-1
    int i = idx & (SS - 1);
    int y = i >> 9;
    int x = i & 511;
    float g = 0.0f;
    if (y > 0 && y < S - 1 && x > 0 && x < S - 1) {
        int base = idx - S - 1;  // (y-1, x-1)
        float a00 = pred[base] * ori[base];
        float a01 = pred[base + 1] * ori[base + 1];
        float a02 = pred[base + 2] * ori[base + 2];
        base += S;
        float a10 = pred[base] * ori[base];
        float a12 = pred[base + 2] * ori[base + 2];
        base += S;
        float a20 = pred[base] * ori[base];
        float a21 = pred[base + 1] * ori[base + 1];
        float a22 = pred[base + 2] * ori[base + 2];
        // cross-correlation (XLA conv does not flip kernels)
        float g0 = -a00 + a02 - 2.0f * a10 + 2.0f * a12 - a20 + a22;
        float g1 = a00 + 2.0f * a01 + a02 - a20 - 2.0f * a21 - a22;
        float g2 = 2.0f * a00 + a01 + a10 - a12 - a21 - 2.0f * a22;
        float g3 = a01 + 2.0f * a02 - a10 + a12 - 2.0f * a20 - a21;
        g = fmaxf(fmaxf(fabsf(g0), fabsf(g1)), fmaxf(fabsf(g2), fabsf(g3)));
    }
    float s = blockReduceSum(g);
    if (threadIdx.x == 0) atomicAdd(gradsum, s);
}

__global__ __launch_bounds__(64) void k_final(const float* __restrict__ maxes,
                                              const float* __restrict__ sums,
                                              const float* __restrict__ gradsum,
                                              float* __restrict__ out) {
    if (threadIdx.x == 0) {
        float dl = 0.0f;
        for (int b = 0; b < BATCH; b++) dl += sums[b] / maxes[b];
        out[0] = dl / (float)(SS * BATCH);
        out[1] = gradsum[0] / (float)(SS * BATCH);
    }
}

extern "C" void kernel_launch(void* const* d_in, const int* in_sizes, int n_in,
                              void* d_out, int out_size, void* d_ws, size_t ws_size,
                              hipStream_t stream) {
    const float* pred = (const float*)d_in[0];
    const float* ptl  = (const float*)d_in[1];
    const float* ori  = (const float*)d_in[2];
    float* out = (float*)d_out;

    float* wsf   = (float*)d_ws;
    float* maxes = wsf;            // as int-bits for atomicMax
    float* sums  = wsf + 8;
    float* grad  = wsf + 16;
    int*   counts = ((int*)d_ws) + 24;
    float* pts   = wsf + 64;

    k_init<<<2, 256, 0, stream>>>(wsf);
    k_find<<<BATCH * SS / 256, 256, 0, stream>>>(ptl, counts, pts);
    k_dmax<<<dim3(SS / 256, BATCH), 256, 0, stream>>>(counts, pts, (int*)maxes);
    k_dsum<<<dim3(SS / 256, BATCH), 256, 0, stream>>>(pred, counts, pts, sums);
    k_grad<<<BATCH * SS / 256, 256, 0, stream>>>(pred, ori, grad);
    k_final<<<1, 64, 0, stream>>>(maxes, sums, grad, out);
}

// Round 2
// 131.811 us; speedup vs baseline: 2.9166x; 2.9166x over previous
//
#include <hip/hip_runtime.h>
#include <math.h>

#define BATCH 8
#define S 512
#define SS (S * S)          // 262144 = 2^18
#define KMAX 16
#define EMPTY_DD 361.1f     // EMPTY_DIST - distance_thre(=1)

// ws float-word layout:
// [0..8)    per-batch max of _distance (atomicMax on int bits; values >= 0)
// [8..16)   per-batch sum of pred*_distance (float atomicAdd)
// [16..24)  per-batch gradient partial sums (float atomicAdd)
// [24..32)  per-batch highlight counts (int)
// [64..64+8*32) per-batch points: 16 x {y,x} floats

__global__ __launch_bounds__(256) void k_init(float* ws) {
    int i = blockIdx.x * 256 + threadIdx.x;
    if (i < 512) ws[i] = 0.0f;
}

__global__ __launch_bounds__(256) void k_find(const float4* __restrict__ ptl,
                                              int* __restrict__ counts,
                                              float* __restrict__ pts) {
    int t = blockIdx.x * 256 + threadIdx.x;      // 0 .. BATCH*SS/4-1
    float4 v4 = ptl[t];
    float v[4] = {v4.x, v4.y, v4.z, v4.w};
    int i0 = t * 4;
#pragma unroll
    for (int j = 0; j < 4; j++) {
        if (v[j] != 0.0f) {
            int idx = i0 + j;
            int b = idx >> 18;
            int i = idx & (SS - 1);
            int slot = atomicAdd(&counts[b], 1);
            if (slot < KMAX) {
                pts[b * 32 + 2 * slot]     = (float)(i >> 9);   // y
                pts[b * 32 + 2 * slot + 1] = (float)(i & 511);  // x
            }
        }
    }
}

// One pass: per-image max(dd), sum(pred*dd), and gradient sum.
// 4 consecutive pixels (same row) per thread.
__global__ __launch_bounds__(256) void k_fused(const float* __restrict__ pred,
                                               const float* __restrict__ ori,
                                               const int* __restrict__ counts,
                                               const float* __restrict__ pts,
                                               int* __restrict__ maxbits,
                                               float* __restrict__ sums,
                                               float* __restrict__ grads) {
    int b = blockIdx.y;
    int i0 = (blockIdx.x * 256 + threadIdx.x) * 4;  // pixel index within image
    int y = i0 >> 9;
    int x0 = i0 & 511;
    int cnt = counts[b];
    if (cnt > KMAX) cnt = KMAX;

    // ---- preload points into registers (fixed-trip, fully unrolled) ----
    float pyk[KMAX], pxk[KMAX];
    const float* pb_pts = pts + b * 32;
#pragma unroll
    for (int k = 0; k < KMAX; k++) {
        bool valid = k < cnt;
        pyk[k] = valid ? pb_pts[2 * k]     : 1e9f;
        pxk[k] = valid ? pb_pts[2 * k + 1] : 1e9f;
    }

    // ---- min squared distance for 4 pixels ----
    float py = (float)y;
    float px = (float)x0;
    float m0 = 1e30f, m1 = 1e30f, m2 = 1e30f, m3 = 1e30f;
#pragma unroll
    for (int k = 0; k < KMAX; k++) {
        float dy = py - pyk[k];
        float dy2 = dy * dy;
        float dx = px - pxk[k];
        float e0 = fmaf(dx, dx, dy2); dx += 1.0f;
        float e1 = fmaf(dx, dx, dy2); dx += 1.0f;
        float e2 = fmaf(dx, dx, dy2); dx += 1.0f;
        float e3 = fmaf(dx, dx, dy2);
        m0 = fminf(m0, e0); m1 = fminf(m1, e1);
        m2 = fminf(m2, e2); m3 = fminf(m3, e3);
    }
    float dd0, dd1, dd2, dd3;
    if (cnt > 0) {
        dd0 = fmaxf(sqrtf(m0) - 1.0f, 0.0f);
        dd1 = fmaxf(sqrtf(m1) - 1.0f, 0.0f);
        dd2 = fmaxf(sqrtf(m2) - 1.0f, 0.0f);
        dd3 = fmaxf(sqrtf(m3) - 1.0f, 0.0f);
    } else {
        dd0 = dd1 = dd2 = dd3 = EMPTY_DD;
    }

    const float* pb = pred + b * SS;
    const float* ob = ori + b * SS;
    float4 p4 = *(const float4*)(pb + i0);
    float lsum = p4.x * dd0 + p4.y * dd1 + p4.z * dd2 + p4.w * dd3;
    float lmax = fmaxf(fmaxf(dd0, dd1), fmaxf(dd2, dd3));

    // ---- gradient (Sobel-4, max-abs, borders zero) for the same 4 pixels ----
    float gsum = 0.0f;
    if (y > 0 && y < S - 1) {
        int xm = x0 - 1; if (xm < 0) xm = 0;            // clamped; only feeds zeroed px
        int xp = x0 + 4; if (xp > S - 1) xp = S - 1;
        float r[3][6];
#pragma unroll
        for (int ri = 0; ri < 3; ri++) {
            int row = (y - 1 + ri) * S;
            const float* pr = pb + row;
            const float* orr = ob + row;
            float4 pv = *(const float4*)(pr + x0);
            float4 ov = *(const float4*)(orr + x0);
            r[ri][0] = pr[xm] * orr[xm];
            r[ri][1] = pv.x * ov.x;
            r[ri][2] = pv.y * ov.y;
            r[ri][3] = pv.z * ov.z;
            r[ri][4] = pv.w * ov.w;
            r[ri][5] = pr[xp] * orr[xp];
        }
#pragma unroll
        for (int j = 0; j < 4; j++) {
            int x = x0 + j;
            if (x == 0 || x == S - 1) continue;
            float a00 = r[0][j], a01 = r[0][j + 1], a02 = r[0][j + 2];
            float a10 = r[1][j],                    a12 = r[1][j + 2];
            float a20 = r[2][j], a21 = r[2][j + 1], a22 = r[2][j + 2];
            float g0 = -a00 + a02 - 2.0f * a10 + 2.0f * a12 - a20 + a22;
            float g1 =  a00 + 2.0f * a01 + a02 - a20 - 2.0f * a21 - a22;
            float g2 =  2.0f * a00 + a01 + a10 - a12 - a21 - 2.0f * a22;
            float g3 =  a01 + 2.0f * a02 - a10 + a12 - 2.0f * a20 - a21;
            gsum += fmaxf(fmaxf(fabsf(g0), fabsf(g1)), fmaxf(fabsf(g2), fabsf(g3)));
        }
    }

    // ---- combined block reduction: sum(lsum), sum(gsum), max(lmax) ----
    __shared__ float sm[4][3];
    int lane = threadIdx.x & 63;
    int wave = threadIdx.x >> 6;
#pragma unroll
    for (int off = 32; off > 0; off >>= 1) {
        lsum += __shfl_down(lsum, off, 64);
        gsum += __shfl_down(gsum, off, 64);
        lmax = fmaxf(lmax, __shfl_down(lmax, off, 64));
    }
    if (lane == 0) { sm[wave][0] = lsum; sm[wave][1] = gsum; sm[wave][2] = lmax; }
    __syncthreads();
    if (wave == 0 && lane < 4) {
        lsum = sm[lane][0]; gsum = sm[lane][1]; lmax = sm[lane][2];
        lsum += __shfl_down(lsum, 2, 64); gsum += __shfl_down(gsum, 2, 64);
        lmax = fmaxf(lmax, __shfl_down(lmax, 2, 64));
        lsum += __shfl_down(lsum, 1, 64); gsum += __shfl_down(gsum, 1, 64);
        lmax = fmaxf(lmax, __shfl_down(lmax, 1, 64));
        if (lane == 0) {
            atomicAdd(&sums[b], lsum);
            atomicAdd(&grads[b], gsum);
            atomicMax(&maxbits[b], __float_as_int(lmax));
        }
    }
}

__global__ __launch_bounds__(64) void k_final(const float* __restrict__ maxes,
                                              const float* __restrict__ sums,
                                              const float* __restrict__ grads,
                                              float* __restrict__ out) {
    if (threadIdx.x == 0) {
        float dl = 0.0f, gl = 0.0f;
        for (int b = 0; b < BATCH; b++) {
            dl += sums[b] / maxes[b];
            gl += grads[b];
        }
        out[0] = dl / (float)(SS * BATCH);
        out[1] = gl / (float)(SS * BATCH);
    }
}

extern "C" void kernel_launch(void* const* d_in, const int* in_sizes, int n_in,
                              void* d_out, int out_size, void* d_ws, size_t ws_size,
                              hipStream_t stream) {
    const float* pred = (const float*)d_in[0];
    const float* ptl  = (const float*)d_in[1];
    const float* ori  = (const float*)d_in[2];
    float* out = (float*)d_out;

    float* wsf    = (float*)d_ws;
    float* maxes  = wsf;             // int-bits via atomicMax
    float* sums   = wsf + 8;
    float* grads  = wsf + 16;
    int*   counts = ((int*)d_ws) + 24;
    float* pts    = wsf + 64;

    k_init<<<2, 256, 0, stream>>>(wsf);
    k_find<<<BATCH * SS / 4 / 256, 256, 0, stream>>>((const float4*)ptl, counts, pts);
    k_fused<<<dim3(SS / 1024, BATCH), 256, 0, stream>>>(pred, ori, counts, pts,
                                                        (int*)maxes, sums, grads);
    k_final<<<1, 64, 0, stream>>>(maxes, sums, grads, out);
}

// Round 3
// 131.233 us; speedup vs baseline: 2.9295x; 1.0044x over previous
//
#include <hip/hip_runtime.h>
#include <math.h>

#define BATCH 8
#define S 512
#define SS (S * S)          // 262144 = 2^18
#define KMAX 16
#define EMPTY_DD 361.1f     // EMPTY_DIST - distance_thre(=1)
#define SENTINEL 1e9f

// ws float-word layout:
// [0..8)    per-batch max of _distance (atomicMax on int bits; values >= 0)
// [8..16)   per-batch sum of pred*_distance (float atomicAdd)
// [16..24)  per-batch gradient partial sums (float atomicAdd)
// [24..32)  per-batch highlight counts (int)
// [64..320) per-batch points SoA: py[16] then px[16]  (b*32 stride)

__global__ __launch_bounds__(512) void k_init(float* ws) {
    int i = threadIdx.x;  // one block of 512
    ws[i] = (i >= 64 && i < 64 + BATCH * 32) ? SENTINEL : 0.0f;
}

__global__ __launch_bounds__(256) void k_find(const float4* __restrict__ ptl,
                                              int* __restrict__ counts,
                                              float* __restrict__ pts) {
    int t = blockIdx.x * 256 + threadIdx.x;      // 0 .. BATCH*SS/4-1
    float4 v4 = ptl[t];
    if (v4.x != 0.0f || v4.y != 0.0f || v4.z != 0.0f || v4.w != 0.0f) {
        float v[4] = {v4.x, v4.y, v4.z, v4.w};
        int i0 = t * 4;
#pragma unroll
        for (int j = 0; j < 4; j++) {
            if (v[j] != 0.0f) {
                int idx = i0 + j;
                int b = idx >> 18;
                int i = idx & (SS - 1);
                int slot = atomicAdd(&counts[b], 1);
                if (slot < KMAX) {
                    pts[b * 32 + slot]        = (float)(i >> 9);   // y
                    pts[b * 32 + 16 + slot]   = (float)(i & 511);  // x
                }
            }
        }
    }
}

// One pass: per-image max(dd), sum(pred*dd), and gradient sum.
// 4 consecutive pixels (same row) per thread.
__global__ __launch_bounds__(256) void k_fused(const float* __restrict__ pred,
                                               const float* __restrict__ ori,
                                               const int* __restrict__ counts,
                                               const float* __restrict__ pts,
                                               int* __restrict__ maxbits,
                                               float* __restrict__ sums,
                                               float* __restrict__ grads) {
    int b = blockIdx.y;
    int i0 = (blockIdx.x * 256 + threadIdx.x) * 4;  // pixel index within image
    int y = i0 >> 9;
    int x0 = i0 & 511;
    int cnt = counts[b];

    // ---- unconditional SoA point load: 8 float4, values land in VGPRs ----
    const float4* pyv = (const float4*)(pts + b * 32);
    const float4* pxv = (const float4*)(pts + b * 32 + 16);
    float pyk[KMAX], pxk[KMAX];
#pragma unroll
    for (int q = 0; q < 4; q++) {
        float4 a = pyv[q];
        pyk[4 * q] = a.x; pyk[4 * q + 1] = a.y; pyk[4 * q + 2] = a.z; pyk[4 * q + 3] = a.w;
        float4 c = pxv[q];
        pxk[4 * q] = c.x; pxk[4 * q + 1] = c.y; pxk[4 * q + 2] = c.z; pxk[4 * q + 3] = c.w;
    }

    // ---- min squared distance for 4 pixels (pure FMA/min, no memory) ----
    float py = (float)y;
    float px = (float)x0;
    float m0 = 1e30f, m1 = 1e30f, m2 = 1e30f, m3 = 1e30f;
#pragma unroll
    for (int k = 0; k < KMAX; k++) {
        float dy = py - pyk[k];
        float dy2 = dy * dy;
        float dx = px - pxk[k];
        float e0 = fmaf(dx, dx, dy2); dx += 1.0f;
        float e1 = fmaf(dx, dx, dy2); dx += 1.0f;
        float e2 = fmaf(dx, dx, dy2); dx += 1.0f;
        float e3 = fmaf(dx, dx, dy2);
        m0 = fminf(m0, e0); m1 = fminf(m1, e1);
        m2 = fminf(m2, e2); m3 = fminf(m3, e3);
    }
    bool has = cnt > 0;
    float dd0 = has ? fmaxf(sqrtf(m0) - 1.0f, 0.0f) : EMPTY_DD;
    float dd1 = has ? fmaxf(sqrtf(m1) - 1.0f, 0.0f) : EMPTY_DD;
    float dd2 = has ? fmaxf(sqrtf(m2) - 1.0f, 0.0f) : EMPTY_DD;
    float dd3 = has ? fmaxf(sqrtf(m3) - 1.0f, 0.0f) : EMPTY_DD;

    const float* pb = pred + b * SS;
    const float* ob = ori + b * SS;
    float4 p4 = *(const float4*)(pb + i0);
    float lsum = p4.x * dd0 + p4.y * dd1 + p4.z * dd2 + p4.w * dd3;
    float lmax = fmaxf(fmaxf(dd0, dd1), fmaxf(dd2, dd3));

    // ---- gradient (Sobel-4, max-abs, borders zero) for the same 4 pixels ----
    float gsum = 0.0f;
    if (y > 0 && y < S - 1) {
        int xm = x0 - 1; if (xm < 0) xm = 0;            // clamped; only feeds zeroed px
        int xp = x0 + 4; if (xp > S - 1) xp = S - 1;
        float r[3][6];
#pragma unroll
        for (int ri = 0; ri < 3; ri++) {
            int row = (y - 1 + ri) * S;
            const float* pr = pb + row;
            const float* orr = ob + row;
            float4 pv = *(const float4*)(pr + x0);
            float4 ov = *(const float4*)(orr + x0);
            r[ri][0] = pr[xm] * orr[xm];
            r[ri][1] = pv.x * ov.x;
            r[ri][2] = pv.y * ov.y;
            r[ri][3] = pv.z * ov.z;
            r[ri][4] = pv.w * ov.w;
            r[ri][5] = pr[xp] * orr[xp];
        }
#pragma unroll
        for (int j = 0; j < 4; j++) {
            int x = x0 + j;
            if (x == 0 || x == S - 1) continue;
            float a00 = r[0][j], a01 = r[0][j + 1], a02 = r[0][j + 2];
            float a10 = r[1][j],                    a12 = r[1][j + 2];
            float a20 = r[2][j], a21 = r[2][j + 1], a22 = r[2][j + 2];
            float g0 = -a00 + a02 - 2.0f * a10 + 2.0f * a12 - a20 + a22;
            float g1 =  a00 + 2.0f * a01 + a02 - a20 - 2.0f * a21 - a22;
            float g2 =  2.0f * a00 + a01 + a10 - a12 - a21 - 2.0f * a22;
            float g3 =  a01 + 2.0f * a02 - a10 + a12 - 2.0f * a20 - a21;
            gsum += fmaxf(fmaxf(fabsf(g0), fabsf(g1)), fmaxf(fabsf(g2), fabsf(g3)));
        }
    }

    // ---- combined block reduction: sum(lsum), sum(gsum), max(lmax) ----
    __shared__ float sm[4][3];
    int lane = threadIdx.x & 63;
    int wave = threadIdx.x >> 6;
#pragma unroll
    for (int off = 32; off > 0; off >>= 1) {
        lsum += __shfl_down(lsum, off, 64);
        gsum += __shfl_down(gsum, off, 64);
        lmax = fmaxf(lmax, __shfl_down(lmax, off, 64));
    }
    if (lane == 0) { sm[wave][0] = lsum; sm[wave][1] = gsum; sm[wave][2] = lmax; }
    __syncthreads();
    if (wave == 0 && lane < 4) {
        lsum = sm[lane][0]; gsum = sm[lane][1]; lmax = sm[lane][2];
        lsum += __shfl_down(lsum, 2, 64); gsum += __shfl_down(gsum, 2, 64);
        lmax = fmaxf(lmax, __shfl_down(lmax, 2, 64));
        lsum += __shfl_down(lsum, 1, 64); gsum += __shfl_down(gsum, 1, 64);
        lmax = fmaxf(lmax, __shfl_down(lmax, 1, 64));
        if (lane == 0) {
            atomicAdd(&sums[b], lsum);
            atomicAdd(&grads[b], gsum);
            atomicMax(&maxbits[b], __float_as_int(lmax));
        }
    }
}

__global__ __launch_bounds__(64) void k_final(const float* __restrict__ maxes,
                                              const float* __restrict__ sums,
                                              const float* __restrict__ grads,
                                              float* __restrict__ out) {
    int lane = threadIdx.x;
    float dl = 0.0f, gl = 0.0f;
    if (lane < BATCH) {
        dl = sums[lane] / maxes[lane];
        gl = grads[lane];
    }
#pragma unroll
    for (int off = 4; off > 0; off >>= 1) {
        dl += __shfl_down(dl, off, 64);
        gl += __shfl_down(gl, off, 64);
    }
    if (lane == 0) {
        out[0] = dl / (float)(SS * BATCH);
        out[1] = gl / (float)(SS * BATCH);
    }
}

extern "C" void kernel_launch(void* const* d_in, const int* in_sizes, int n_in,
                              void* d_out, int out_size, void* d_ws, size_t ws_size,
                              hipStream_t stream) {
    const float* pred = (const float*)d_in[0];
    const float* ptl  = (const float*)d_in[1];
    const float* ori  = (const float*)d_in[2];
    float* out = (float*)d_out;

    float* wsf    = (float*)d_ws;
    float* maxes  = wsf;             // int-bits via atomicMax
    float* sums   = wsf + 8;
    float* grads  = wsf + 16;
    int*   counts = ((int*)d_ws) + 24;
    float* pts    = wsf + 64;

    k_init<<<1, 512, 0, stream>>>(wsf);
    k_find<<<BATCH * SS / 4 / 256, 256, 0, stream>>>((const float4*)ptl, counts, pts);
    k_fused<<<dim3(SS / 1024, BATCH), 256, 0, stream>>>(pred, ori, counts, pts,
                                                        (int*)maxes, sums, grads);
    k_final<<<1, 64, 0, stream>>>(maxes, sums, grads, out);
}

// Round 4
// 116.024 us; speedup vs baseline: 3.3135x; 1.1311x over previous
//
#include <hip/hip_runtime.h>
#include <math.h>

#define BATCH 8
#define S 512
#define SS (S * S)          // 262144 = 2^18
#define KMAX 16
#define EMPTY_DD 361.1f     // EMPTY_DIST - distance_thre(=1)
#define SENT 1e9f
#define NBLK (BATCH * S / 4)   // 1024 fused blocks (4 rows per block)

// ws layout (zeroed by hipMemsetAsync, first 2048 bytes):
// f[0..8)    per-batch max of _distance (int-bits atomicMax; values >= 0)
// f[8..16)   per-batch sum of pred*_distance
// f[16..24)  per-batch gradient sums
// i[24..32)  per-batch highlight counts
// i[32]      done-counter (last-block finalize)
// f[64..320) per-batch points SoA: py[16] | px[16]  (stride 32)

__global__ __launch_bounds__(256) void k_find(const float4* __restrict__ ptl,
                                              int* __restrict__ counts,
                                              float* __restrict__ pts) {
    int t = blockIdx.x * 256 + threadIdx.x;      // 0 .. BATCH*SS/8-1
    float4 a = ptl[2 * t];
    float4 c = ptl[2 * t + 1];
    if (a.x != 0.0f || a.y != 0.0f || a.z != 0.0f || a.w != 0.0f ||
        c.x != 0.0f || c.y != 0.0f || c.z != 0.0f || c.w != 0.0f) {
        float v[8] = {a.x, a.y, a.z, a.w, c.x, c.y, c.z, c.w};
        int i0 = t * 8;
#pragma unroll
        for (int j = 0; j < 8; j++) {
            if (v[j] != 0.0f) {
                int idx = i0 + j;
                int b = idx >> 18;
                int i = idx & (SS - 1);
                int slot = atomicAdd(&counts[b], 1);
                if (slot < KMAX) {
                    pts[b * 32 + slot]      = (float)(i >> 9);   // y
                    pts[b * 32 + 16 + slot] = (float)(i & 511);  // x
                }
            }
        }
    }
}

// One wave == one image row (64 lanes x 8 px). Block = 4 rows.
// Computes per-image max(dd), sum(pred*dd), gradient sum; last block finalizes.
__global__ __launch_bounds__(256, 4) void k_fused(const float* __restrict__ pred,
                                                  const float* __restrict__ ori,
                                                  const int* __restrict__ counts,
                                                  const float* __restrict__ pts,
                                                  float* ws,
                                                  float* __restrict__ out) {
    int* wsi = (int*)ws;
    int b = blockIdx.y;
    int wave = threadIdx.x >> 6;
    int lane = threadIdx.x & 63;
    int y = (blockIdx.x << 2) + wave;   // row (wave-uniform)
    int x0 = lane << 3;
    int cnt = counts[b];

    // ---- points: 8 unconditional float4 loads, invalid slots masked to SENT ----
    float pyk[KMAX], pxk[KMAX];
    {
        const float4* pyv = (const float4*)(pts + b * 32);
        const float4* pxv = (const float4*)(pts + b * 32 + 16);
#pragma unroll
        for (int q = 0; q < 4; q++) {
            float4 a = pyv[q];
            pyk[4 * q] = a.x; pyk[4 * q + 1] = a.y; pyk[4 * q + 2] = a.z; pyk[4 * q + 3] = a.w;
            float4 c = pxv[q];
            pxk[4 * q] = c.x; pxk[4 * q + 1] = c.y; pxk[4 * q + 2] = c.z; pxk[4 * q + 3] = c.w;
        }
#pragma unroll
        for (int k = 0; k < KMAX; k++) {
            bool valid = k < cnt;
            pyk[k] = valid ? pyk[k] : SENT;
            pxk[k] = valid ? pxk[k] : SENT;
        }
    }

    // ---- min squared distance for 8 pixels ----
    float fy = (float)y;
    float fx = (float)x0;
    float m[8];
#pragma unroll
    for (int j = 0; j < 8; j++) m[j] = 1e30f;
#pragma unroll
    for (int k = 0; k < KMAX; k++) {
        float dy = fy - pyk[k];
        float dy2 = dy * dy;
        float dx = fx - pxk[k];
#pragma unroll
        for (int j = 0; j < 8; j++) {
            float d = dx + (float)j;
            m[j] = fminf(m[j], fmaf(d, d, dy2));
        }
    }
    bool has = cnt > 0;
    float dd[8];
#pragma unroll
    for (int j = 0; j < 8; j++)
        dd[j] = has ? fmaxf(sqrtf(m[j]) - 1.0f, 0.0f) : EMPTY_DD;

    const float* pb = pred + b * SS;
    const float* ob = ori + b * SS;
    const float4* prow = (const float4*)(pb + y * S + x0);
    float4 pA = prow[0], pB = prow[1];

    float lsum = pA.x * dd[0] + pA.y * dd[1] + pA.z * dd[2] + pA.w * dd[3] +
                 pB.x * dd[4] + pB.y * dd[5] + pB.z * dd[6] + pB.w * dd[7];
    float lmax = fmaxf(fmaxf(fmaxf(dd[0], dd[1]), fmaxf(dd[2], dd[3])),
                       fmaxf(fmaxf(dd[4], dd[5]), fmaxf(dd[6], dd[7])));

    // ---- gradient: halo via shuffles; wave-uniform skip on border rows ----
    float gsum = 0.0f;
    if (y > 0 && y < S - 1) {
        float r[3][10];
#pragma unroll
        for (int ri = 0; ri < 3; ri++) {
            int yy = y - 1 + ri;
            const float4* pr  = (const float4*)(pb + yy * S + x0);
            const float4* orr = (const float4*)(ob + yy * S + x0);
            float4 p0 = (ri == 1) ? pA : pr[0];
            float4 p1 = (ri == 1) ? pB : pr[1];
            float4 o0 = orr[0], o1 = orr[1];
            r[ri][1] = p0.x * o0.x; r[ri][2] = p0.y * o0.y;
            r[ri][3] = p0.z * o0.z; r[ri][4] = p0.w * o0.w;
            r[ri][5] = p1.x * o1.x; r[ri][6] = p1.y * o1.y;
            r[ri][7] = p1.z * o1.z; r[ri][8] = p1.w * o1.w;
            r[ri][0] = __shfl_up(r[ri][8], 1, 64);    // left halo (lane0: dead, x=0 zeroed)
            r[ri][9] = __shfl_down(r[ri][1], 1, 64);  // right halo (lane63: dead, x=511 zeroed)
        }
#pragma unroll
        for (int j = 0; j < 8; j++) {
            float a00 = r[0][j], a01 = r[0][j + 1], a02 = r[0][j + 2];
            float a10 = r[1][j],                    a12 = r[1][j + 2];
            float a20 = r[2][j], a21 = r[2][j + 1], a22 = r[2][j + 2];
            float g0 = -a00 + a02 - 2.0f * a10 + 2.0f * a12 - a20 + a22;
            float g1 =  a00 + 2.0f * a01 + a02 - a20 - 2.0f * a21 - a22;
            float g2 =  2.0f * a00 + a01 + a10 - a12 - a21 - 2.0f * a22;
            float g3 =  a01 + 2.0f * a02 - a10 + a12 - 2.0f * a20 - a21;
            float gv = fmaxf(fmaxf(fabsf(g0), fabsf(g1)), fmaxf(fabsf(g2), fabsf(g3)));
            bool edge = (lane == 0 && j == 0) || (lane == 63 && j == 7);
            gsum += edge ? 0.0f : gv;
        }
    }

    // ---- block reduction: sum(lsum), sum(gsum), max(lmax) ----
    __shared__ float sm[4][3];
#pragma unroll
    for (int off = 32; off > 0; off >>= 1) {
        lsum += __shfl_down(lsum, off, 64);
        gsum += __shfl_down(gsum, off, 64);
        lmax = fmaxf(lmax, __shfl_down(lmax, off, 64));
    }
    if (lane == 0) { sm[wave][0] = lsum; sm[wave][1] = gsum; sm[wave][2] = lmax; }
    __syncthreads();
    if (threadIdx.x == 0) {
#pragma unroll
        for (int w = 1; w < 4; w++) {
            lsum += sm[w][0];
            gsum += sm[w][1];
            lmax = fmaxf(lmax, sm[w][2]);
        }
        atomicAdd(&ws[8 + b], lsum);
        atomicAdd(&ws[16 + b], gsum);
        atomicMax(&wsi[b], __float_as_int(lmax));
        __threadfence();
        int t = atomicAdd(&wsi[32], 1);
        if (t == NBLK - 1) {
            __threadfence();
            float dl = 0.0f, gl = 0.0f;
#pragma unroll
            for (int bb = 0; bb < BATCH; bb++) {
                float smax = __int_as_float(atomicAdd(&wsi[bb], 0));
                float ssum = atomicAdd(&ws[8 + bb], 0.0f);
                float sgrd = atomicAdd(&ws[16 + bb], 0.0f);
                dl += ssum / smax;
                gl += sgrd;
            }
            out[0] = dl / (float)(SS * BATCH);
            out[1] = gl / (float)(SS * BATCH);
        }
    }
}

extern "C" void kernel_launch(void* const* d_in, const int* in_sizes, int n_in,
                              void* d_out, int out_size, void* d_ws, size_t ws_size,
                              hipStream_t stream) {
    const float* pred = (const float*)d_in[0];
    const float* ptl  = (const float*)d_in[1];
    const float* ori  = (const float*)d_in[2];
    float* out = (float*)d_out;

    float* wsf    = (float*)d_ws;
    int*   counts = ((int*)d_ws) + 24;
    float* pts    = wsf + 64;

    hipMemsetAsync(d_ws, 0, 2048, stream);
    k_find<<<BATCH * SS / 8 / 256, 256, 0, stream>>>((const float4*)ptl, counts, pts);
    k_fused<<<dim3(S / 4, BATCH), 256, 0, stream>>>(pred, ori, counts, pts, wsf, out);
}

// Round 6
// 109.888 us; speedup vs baseline: 3.4985x; 1.0558x over previous
//
#include <hip/hip_runtime.h>
#include <math.h>

#define BATCH 8
#define S 512
#define SS (S * S)          // 262144
#define KMAX 16
#define EMPTY_DD 361.1f     // EMPTY_DIST - distance_thre(=1)
#define SENT 1e9f
#define NBLK 256            // 32 blocks/image, 16 rows/block
#define IMB 32
#define RPB 16
#define MAGIC1 0x5A5A0000
#define MAGIC2 0x3C3C3C3C
#define SPIN_MAX (1 << 22)

// ws int layout (NO initialization required — flags are magic-tagged):
// [0..256)       flag1[blk] = MAGIC1 | local_point_count
// [256..4352)    g_pts[blk*16 + k] : packed pixel idx (y*512+x) within image
// f[4352..4608)  per-block partial lsum
// f[4608..4864)  per-block partial gsum
// f[4864..5120)  per-block partial lmax
// [5120..5376)   flag2[blk] = MAGIC2

__global__ __launch_bounds__(256, 2) void k_all(const float* __restrict__ pred,
                                                const float* __restrict__ ptl,
                                                const float* __restrict__ ori,
                                                int* __restrict__ wsi,
                                                float* __restrict__ out) {
    float* wsf = (float*)wsi;
    int tid = threadIdx.x;
    int blk = blockIdx.x;
    int b  = blk >> 5;           // image
    int rg = blk & 31;           // row-group (16 rows)
    int wave = tid >> 6;
    int lane = tid & 63;

    __shared__ int l_cnt;
    __shared__ int l_fnd[16];
    __shared__ int l_list[16];
    __shared__ int l_total;
    __shared__ float sm[4][3];
    __shared__ float fin[8][3];

    if (tid == 0) l_cnt = 0;
    __syncthreads();

    // ---- phase A: scan own 16 rows of pt_label for highlight points ----
    {
        const float4* p4 = (const float4*)(ptl + b * SS + rg * (RPB * S)) + tid * 8;
#pragma unroll
        for (int q = 0; q < 8; q++) {
            float4 v = p4[q];
            float s = v.x + v.y + v.z + v.w;   // labels are >= 0
            if (s != 0.0f) {
                int i0 = rg * (RPB * S) + tid * 32 + q * 4;
                float c[4] = {v.x, v.y, v.z, v.w};
#pragma unroll
                for (int j = 0; j < 4; j++) {
                    if (c[j] != 0.0f) {
                        int slot = atomicAdd(&l_cnt, 1);
                        if (slot < 16) l_fnd[slot] = i0 + j;
                    }
                }
            }
        }
    }
    __syncthreads();
    int lcnt = l_cnt; if (lcnt > 16) lcnt = 16;
    if (tid < lcnt) wsi[256 + blk * 16 + tid] = l_fnd[tid];
    __threadfence();
    __syncthreads();
    if (tid == 0) {
        __threadfence();
        __hip_atomic_store(&wsi[blk], MAGIC1 | lcnt,
                           __ATOMIC_RELEASE, __HIP_MEMORY_SCOPE_AGENT);
    }

    // ---- per-image point barrier (bounded spin; all blocks co-resident) ----
    {
        bool ok = (tid >= IMB);
        for (int g = 0; g < SPIN_MAX; g++) {
            if (!ok) {
                int v = __hip_atomic_load(&wsi[(b << 5) + tid],
                                          __ATOMIC_RELAXED, __HIP_MEMORY_SCOPE_AGENT);
                ok = ((v & 0xFFFF0000) == MAGIC1);
            }
            if (__syncthreads_and(ok)) break;
        }
    }

    // ---- gather this image's points (wave 0, lanes 0..31) ----
    if (wave == 0) {
        int cj = 0;
        if (lane < IMB) {
            int v = __hip_atomic_load(&wsi[(b << 5) + lane],
                                      __ATOMIC_RELAXED, __HIP_MEMORY_SCOPE_AGENT);
            cj = v & 0xFFFF;
        }
        int pre = cj;
#pragma unroll
        for (int d = 1; d < 32; d <<= 1) {
            int t = __shfl_up(pre, d, 64);
            if (lane >= d && lane < 32) pre += t;
        }
        if (lane == 31) l_total = (pre > 16) ? 16 : pre;
        int off = pre - cj;   // exclusive prefix
        if (lane < IMB) {
            for (int k = 0; k < cj; k++) {
                if (off + k < 16)
                    l_list[off + k] = __hip_atomic_load(
                        &wsi[256 + ((b << 5) + lane) * 16 + k],
                        __ATOMIC_RELAXED, __HIP_MEMORY_SCOPE_AGENT);
            }
        }
    }
    __syncthreads();

    int cnt = l_total;
    bool has = cnt > 0;
    float pyk[KMAX], pxk[KMAX];
#pragma unroll
    for (int k = 0; k < KMAX; k++) {
        if (k < cnt) {
            int pk = l_list[k];
            pyk[k] = (float)(pk >> 9);
            pxk[k] = (float)(pk & 511);
        } else { pyk[k] = SENT; pxk[k] = SENT; }
    }

    // ---- phase C: fused distance + gradient, 4 rows per wave ----
    const float* pb = pred + b * SS;
    const float* ob = ori + b * SS;
    int x0 = lane << 3;
    float fx = (float)x0;
    float lsum = 0.0f, gsum = 0.0f, lmax = 0.0f;
    int ybase = rg * RPB + wave * 4;

    for (int it = 0; it < 4; it++) {
        int y = ybase + it;      // wave-uniform
        float fy = (float)y;

        float m[8];
#pragma unroll
        for (int j = 0; j < 8; j++) m[j] = 1e30f;
#pragma unroll
        for (int k = 0; k < KMAX; k++) {
            float dy = fy - pyk[k];
            float dy2 = dy * dy;
            float dx = fx - pxk[k];
#pragma unroll
            for (int j = 0; j < 8; j++) {
                float d = dx + (float)j;
                m[j] = fminf(m[j], fmaf(d, d, dy2));
            }
        }
        float dd[8];
#pragma unroll
        for (int j = 0; j < 8; j++)
            dd[j] = has ? fmaxf(sqrtf(m[j]) - 1.0f, 0.0f) : EMPTY_DD;

        const float4* prow = (const float4*)(pb + y * S + x0);
        float4 pA = prow[0], pB = prow[1];
        lsum += pA.x * dd[0] + pA.y * dd[1] + pA.z * dd[2] + pA.w * dd[3] +
                pB.x * dd[4] + pB.y * dd[5] + pB.z * dd[6] + pB.w * dd[7];
        float rmax = fmaxf(fmaxf(fmaxf(dd[0], dd[1]), fmaxf(dd[2], dd[3])),
                           fmaxf(fmaxf(dd[4], dd[5]), fmaxf(dd[6], dd[7])));
        lmax = fmaxf(lmax, rmax);

        if (y > 0 && y < S - 1) {
            float r[3][10];
#pragma unroll
            for (int ri = 0; ri < 3; ri++) {
                int yy = y - 1 + ri;
                const float4* pr  = (const float4*)(pb + yy * S + x0);
                const float4* orr = (const float4*)(ob + yy * S + x0);
                float4 p0 = (ri == 1) ? pA : pr[0];
                float4 p1 = (ri == 1) ? pB : pr[1];
                float4 o0 = orr[0], o1 = orr[1];
                r[ri][1] = p0.x * o0.x; r[ri][2] = p0.y * o0.y;
                r[ri][3] = p0.z * o0.z; r[ri][4] = p0.w * o0.w;
                r[ri][5] = p1.x * o1.x; r[ri][6] = p1.y * o1.y;
                r[ri][7] = p1.z * o1.z; r[ri][8] = p1.w * o1.w;
                r[ri][0] = __shfl_up(r[ri][8], 1, 64);    // lane0 value dead (x=0 zeroed)
                r[ri][9] = __shfl_down(r[ri][1], 1, 64);  // lane63 value dead (x=511 zeroed)
            }
#pragma unroll
            for (int j = 0; j < 8; j++) {
                float a00 = r[0][j], a01 = r[0][j + 1], a02 = r[0][j + 2];
                float a10 = r[1][j],                    a12 = r[1][j + 2];
                float a20 = r[2][j], a21 = r[2][j + 1], a22 = r[2][j + 2];
                float g0 = -a00 + a02 - 2.0f * a10 + 2.0f * a12 - a20 + a22;
                float g1 =  a00 + 2.0f * a01 + a02 - a20 - 2.0f * a21 - a22;
                float g2 =  2.0f * a00 + a01 + a10 - a12 - a21 - 2.0f * a22;
                float g3 =  a01 + 2.0f * a02 - a10 + a12 - 2.0f * a20 - a21;
                float gv = fmaxf(fmaxf(fabsf(g0), fabsf(g1)), fmaxf(fabsf(g2), fabsf(g3)));
                bool edge = (lane == 0 && j == 0) || (lane == 63 && j == 7);
                gsum += edge ? 0.0f : gv;
            }
        }
    }

    // ---- block reduce + publish partials ----
#pragma unroll
    for (int off = 32; off > 0; off >>= 1) {
        lsum += __shfl_down(lsum, off, 64);
        gsum += __shfl_down(gsum, off, 64);
        lmax = fmaxf(lmax, __shfl_down(lmax, off, 64));
    }
    if (lane == 0) { sm[wave][0] = lsum; sm[wave][1] = gsum; sm[wave][2] = lmax; }
    __syncthreads();
    if (tid == 0) {
#pragma unroll
        for (int w = 1; w < 4; w++) {
            lsum += sm[w][0];
            gsum += sm[w][1];
            lmax = fmaxf(lmax, sm[w][2]);
        }
        wsf[4352 + blk] = lsum;
        wsf[4608 + blk] = gsum;
        wsf[4864 + blk] = lmax;
        __threadfence();
        __hip_atomic_store(&wsi[5120 + blk], MAGIC2,
                           __ATOMIC_RELEASE, __HIP_MEMORY_SCOPE_AGENT);
    }

    // ---- block 0: wait for all partials, finalize ----
    if (blk == 0) {
        bool ok = false;
        for (int g = 0; g < SPIN_MAX; g++) {
            if (!ok)
                ok = (__hip_atomic_load(&wsi[5120 + tid],
                                        __ATOMIC_RELAXED, __HIP_MEMORY_SCOPE_AGENT) == MAGIC2);
            if (__syncthreads_and(ok)) break;
        }
        __threadfence();
        float ls = __hip_atomic_load(&wsf[4352 + tid], __ATOMIC_RELAXED, __HIP_MEMORY_SCOPE_AGENT);
        float gs = __hip_atomic_load(&wsf[4608 + tid], __ATOMIC_RELAXED, __HIP_MEMORY_SCOPE_AGENT);
        float lm = __hip_atomic_load(&wsf[4864 + tid], __ATOMIC_RELAXED, __HIP_MEMORY_SCOPE_AGENT);
        // segment-reduce 32-lane groups (one image per group of 32 tids)
#pragma unroll
        for (int off = 16; off > 0; off >>= 1) {
            ls += __shfl_down(ls, off, 32);
            gs += __shfl_down(gs, off, 32);
            lm = fmaxf(lm, __shfl_down(lm, off, 32));
        }
        if ((lane & 31) == 0) {
            int img = (wave << 1) | (lane >> 5);
            fin[img][0] = ls; fin[img][1] = gs; fin[img][2] = lm;
        }
        __syncthreads();
        if (tid == 0) {
            float dl = 0.0f, gl = 0.0f;
#pragma unroll
            for (int bb = 0; bb < BATCH; bb++) {
                dl += fin[bb][0] / fin[bb][2];
                gl += fin[bb][1];
            }
            out[0] = dl / (float)(SS * BATCH);
            out[1] = gl / (float)(SS * BATCH);
        }
    }
}

extern "C" void kernel_launch(void* const* d_in, const int* in_sizes, int n_in,
                              void* d_out, int out_size, void* d_ws, size_t ws_size,
                              hipStream_t stream) {
    const float* pred = (const float*)d_in[0];
    const float* ptl  = (const float*)d_in[1];
    const float* ori  = (const float*)d_in[2];
    float* out = (float*)d_out;
    int* wsi = (int*)d_ws;

    k_all<<<NBLK, 256, 0, stream>>>(pred, ptl, ori, wsi, out);
}